// Round 1
// baseline (342.223 us; speedup 1.0000x reference)
//
#include <hip/hip_runtime.h>
#include <hip/hip_bf16.h>

typedef float f32x4 __attribute__((ext_vector_type(4)));
typedef __bf16 bf16x8 __attribute__((ext_vector_type(8)));
typedef unsigned short u16;
typedef unsigned short u16x4 __attribute__((ext_vector_type(4)));
typedef unsigned short u16x8 __attribute__((ext_vector_type(8)));

#define BM 128
#define BN 128
#define BK 32
#define NT 256

// round-to-nearest-even fp32 -> bf16 (unbiased; bias would accumulate across K)
__device__ __forceinline__ u16 f2bf(float f) {
  unsigned u = __builtin_bit_cast(unsigned, f);
  u += 0x7fffu + ((u >> 16) & 1u);
  return (u16)(u >> 16);
}

// Grouped GEMM: Out[m, n] = act( sum_k A[m,k] * B[e][n,k] + bias[e][n] )
// A is [T][K] (fp32 or bf16 raw-u16), B is [E][N][K] fp32, rows grouped by expert.
template<bool A_BF16, bool DO_GELU, bool OUT_BF16>
__global__ __launch_bounds__(NT)
void ffn_gemm(const void* __restrict__ Ain, const float* __restrict__ Bw,
              const float* __restrict__ bias, void* __restrict__ Out,
              const int* __restrict__ counts, int E, int T, int N, int K)
{
  // blockIdx.y -> (expert, row-tile) via prefix over runtime counts
  int mt = blockIdx.y;
  int row0 = 0, cnt = 0, e = 0;
  for (; e < E; ++e) {
    cnt = counts[e];
    int nt = (cnt + BM - 1) / BM;
    if (mt < nt) break;
    mt -= nt; row0 += cnt;
  }
  if (e >= E) return;
  int valid = cnt - mt * BM; if (valid > BM) valid = BM;
  row0 += mt * BM;
  const int n0 = blockIdx.x * BN;

  const float* Be = Bw + (long long)e * N * K;
  const float* be = bias + (long long)e * N;

  __shared__ u16 As[2][BM][BK];
  __shared__ u16 Bs[2][BN][BK];

  const int t = threadIdx.x;
  const int lane = t & 63;
  const int w = t >> 6, wr = w >> 1, wc = w & 1;  // 2x2 waves -> 64x64 each

  f32x4 acc[4][4];
#pragma unroll
  for (int i = 0; i < 4; ++i)
#pragma unroll
    for (int j = 0; j < 4; ++j) acc[i][j] = (f32x4){0.f, 0.f, 0.f, 0.f};

  const int NKT = K / BK;

  float rA[16]; u16x8 rAu[2]; float rB[16];

  auto load_tile = [&](int kt) {
    const int k0 = kt * BK;
    if constexpr (!A_BF16) {
      const float* Af = (const float*)Ain;
#pragma unroll
      for (int i = 0; i < 4; ++i) {
        int c = i * NT + t;
        int row = c >> 3, col = (c & 7) << 2;
        int gr = row0 + row; if (gr > T - 1) gr = T - 1;
        f32x4 v = *(const f32x4*)(Af + (long long)gr * K + k0 + col);
        rA[i*4+0] = v[0]; rA[i*4+1] = v[1]; rA[i*4+2] = v[2]; rA[i*4+3] = v[3];
      }
    } else {
      const u16* Ab = (const u16*)Ain;
#pragma unroll
      for (int i = 0; i < 2; ++i) {
        int c = i * NT + t;
        int row = c >> 2, col = (c & 3) << 3;
        int gr = row0 + row; if (gr > T - 1) gr = T - 1;
        rAu[i] = *(const u16x8*)(Ab + (long long)gr * K + k0 + col);
      }
    }
#pragma unroll
    for (int i = 0; i < 4; ++i) {
      int c = i * NT + t;
      int row = c >> 3, col = (c & 7) << 2;
      f32x4 v = *(const f32x4*)(Be + (long long)(n0 + row) * K + k0 + col);
      rB[i*4+0] = v[0]; rB[i*4+1] = v[1]; rB[i*4+2] = v[2]; rB[i*4+3] = v[3];
    }
  };

  // XOR-swizzle on 16B granules: physical granule = kg ^ ((row>>1)&3)
  auto store_tile = [&](int buf) {
    if constexpr (!A_BF16) {
#pragma unroll
      for (int i = 0; i < 4; ++i) {
        int c = i * NT + t;
        int row = c >> 3, col = (c & 7) << 2;
        int kg = (col >> 3) ^ ((row >> 1) & 3);
        int off = kg * 8 + ((col >> 2) & 1) * 4;
        u16x4 pk = { f2bf(rA[i*4+0]), f2bf(rA[i*4+1]), f2bf(rA[i*4+2]), f2bf(rA[i*4+3]) };
        *(u16x4*)&As[buf][row][off] = pk;
      }
    } else {
#pragma unroll
      for (int i = 0; i < 2; ++i) {
        int c = i * NT + t;
        int row = c >> 2, col = (c & 3) << 3;
        int kg = (col >> 3) ^ ((row >> 1) & 3);
        *(u16x8*)&As[buf][row][kg * 8] = rAu[i];
      }
    }
#pragma unroll
    for (int i = 0; i < 4; ++i) {
      int c = i * NT + t;
      int row = c >> 3, col = (c & 7) << 2;
      int kg = (col >> 3) ^ ((row >> 1) & 3);
      int off = kg * 8 + ((col >> 2) & 1) * 4;
      u16x4 pk = { f2bf(rB[i*4+0]), f2bf(rB[i*4+1]), f2bf(rB[i*4+2]), f2bf(rB[i*4+3]) };
      *(u16x4*)&Bs[buf][row][off] = pk;
    }
  };

  load_tile(0);
  store_tile(0);
  __syncthreads();

  for (int kt = 0; kt < NKT; ++kt) {
    const int cur = kt & 1;
    if (kt + 1 < NKT) load_tile(kt + 1);   // issue next-tile global loads before MFMA

    bf16x8 af[4], bfr[4];
    const int rl = lane & 15;
    const int kg = (lane >> 4) ^ ((rl >> 1) & 3);
#pragma unroll
    for (int mf = 0; mf < 4; ++mf)
      af[mf] = __builtin_bit_cast(bf16x8, *(const u16x8*)&As[cur][wr*64 + mf*16 + rl][kg*8]);
#pragma unroll
    for (int nf = 0; nf < 4; ++nf)
      bfr[nf] = __builtin_bit_cast(bf16x8, *(const u16x8*)&Bs[cur][wc*64 + nf*16 + rl][kg*8]);
#pragma unroll
    for (int mf = 0; mf < 4; ++mf)
#pragma unroll
      for (int nf = 0; nf < 4; ++nf)
        acc[mf][nf] = __builtin_amdgcn_mfma_f32_16x16x32_bf16(af[mf], bfr[nf], acc[mf][nf], 0, 0, 0);

    if (kt + 1 < NKT) {
      store_tile(cur ^ 1);   // write other buffer; one barrier per K-step
      __syncthreads();
    }
  }

  // epilogue: C/D layout col = lane&15, row = (lane>>4)*4 + r  [verified m89/m91]
  const int cl = lane & 15, rg = lane >> 4;
#pragma unroll
  for (int mf = 0; mf < 4; ++mf) {
#pragma unroll
    for (int nf = 0; nf < 4; ++nf) {
      int gcol = n0 + wc*64 + nf*16 + cl;
      float bv = be[gcol];
#pragma unroll
      for (int r = 0; r < 4; ++r) {
        int lrow = wr*64 + mf*16 + rg*4 + r;
        if (lrow < valid) {
          float v = acc[mf][nf][r] + bv;
          if constexpr (DO_GELU)
            v = 0.5f * v * (1.0f + erff(v * 0.70710678118654752f));
          long long idx = (long long)(row0 + lrow) * N + gcol;
          if constexpr (OUT_BF16) ((u16*)Out)[idx] = f2bf(v);
          else                    ((float*)Out)[idx] = v;
        }
      }
    }
  }
}

extern "C" void kernel_launch(void* const* d_in, const int* in_sizes, int n_in,
                              void* d_out, int out_size, void* d_ws, size_t ws_size,
                              hipStream_t stream) {
  const float* inp = (const float*)d_in[0];
  const float* w1  = (const float*)d_in[1];
  const float* b1  = (const float*)d_in[2];
  const float* w2  = (const float*)d_in[3];
  const float* b2  = (const float*)d_in[4];
  const int* cnts  = (const int*)d_in[5];

  const int E = in_sizes[5];
  const int H = in_sizes[2] / E;       // 4096
  const int D = in_sizes[4] / E;       // 1024
  const int T = in_sizes[0] / D;       // 8192

  u16* hbuf = (u16*)d_ws;              // T*H bf16 intermediate (64 MB)

  const int tiles = (T + BM - 1) / BM + E;  // upper bound on sum of per-expert row-tiles
  dim3 blk(NT);

  dim3 g1(H / BN, tiles);
  ffn_gemm<false, true, true><<<g1, blk, 0, stream>>>(
      (const void*)inp, w1, b1, (void*)hbuf, cnts, E, T, H, D);

  dim3 g2(D / BN, tiles);
  ffn_gemm<true, false, false><<<g2, blk, 0, stream>>>(
      (const void*)hbuf, w2, b2, d_out, cnts, E, T, D, H);
}